// Round 19
// baseline (119.214 us; speedup 1.0000x reference)
//
#include <hip/hip_runtime.h>

// RelationMemory — Round 19: dependency-exact regrouping of PROVEN bodies.
// proj role has NO dependency on embed/compose -> merge all three into one
// first kernel (proj's HBM window absorbs embed+compose CU work). ht becomes
// standalone (exposed ~7us < the ~10us pre1b window it replaces). k_neg/memupd
// byte-identical to round 16/18 (117.6us).
//
// Chain: stage1(proj || embed || compose) -> proj4 -> ht -> k_neg(+copy) -> memupd
//
// Algebra: linear(linear(x,Wm,bm),Wh,bh) == linear(x, Wh@Wm, Wh@bm+bh).
// MFMA: v_mfma_f32_16x16x32_bf16, fp32 via bf16 hi/lo split, 3 products
// (ah*bh + ah*bl + al*bh), rel err ~2^-17.
// Fragments: A row=lane&15, k=(lane>>4)*8+e; B col=lane&15; D row=(lane>>4)*4+r.

#define BB   128
#define DD   128
#define KK   16
#define NMEM 100000

static constexpr float INV_T = 1.0f / 0.07f;

// ws layout (float offsets)
#define WS_SE    0
#define WS_TE    16384
#define WS_MTV   32768
#define WS_MTQ   49152
#define WS_MSV   65536
#define WS_MSPQ  81920
#define WS_HT    98304            // 16384*128 floats -> ends 2195456
#define FR_TS_HI 2195456          // frag arrays: 16384 shorts = 8192 floats each
#define FR_TS_LO 2203648
#define FR_T_HI  2211840
#define FR_T_LO  2220032
#define BC_TS    2244608          // 128 floats
#define BC_T     2244736
#define WS_PROJ  2244864          // 100000*128 floats (51.2 MB)
#define OUT_MEM  278528           // memory_new offset in d_out

typedef __attribute__((ext_vector_type(8))) short short8v;
typedef __attribute__((ext_vector_type(4))) float f32x4;

// ---- cheap split: hi = bf16 half-up(x), lo = bf16 half-up(x - hi) ----
__device__ inline void split2(float x0, float x1, unsigned& hi, unsigned& lo) {
    unsigned u0 = __float_as_uint(x0), u1 = __float_as_uint(x1);
    unsigned h0 = (u0 + 0x8000u) & 0xffff0000u;
    unsigned h1 = (u1 + 0x8000u) & 0xffff0000u;
    float l0 = x0 - __uint_as_float(h0);
    float l1 = x1 - __uint_as_float(h1);
    unsigned v0 = __float_as_uint(l0) + 0x8000u;
    unsigned v1 = __float_as_uint(l1) + 0x8000u;
    hi = __builtin_amdgcn_perm(h1, h0, 0x07060302u);
    lo = __builtin_amdgcn_perm(v1, v0, 0x07060302u);
}

__device__ inline void split8(const float4& x0, const float4& x1, short8v& h8, short8v& l8) {
    uint4 H, L;
    split2(x0.x, x0.y, H.x, L.x);
    split2(x0.z, x0.w, H.y, L.y);
    split2(x1.x, x1.y, H.z, L.z);
    split2(x1.z, x1.w, H.w, L.w);
    h8 = *(short8v*)&H;
    l8 = *(short8v*)&L;
}

// scalar split (matches split2 bit-exactly)
__device__ inline void splits(float x, unsigned short& h, unsigned short& l) {
    unsigned u = __float_as_uint(x);
    unsigned hu = (u + 0x8000u) & 0xffff0000u;
    float lf = x - __uint_as_float(hu);
    h = (unsigned short)(hu >> 16);
    l = (unsigned short)((__float_as_uint(lf) + 0x8000u) >> 16);
}

// ---------------------------------------------------------------- k_stage1
// blocks 0..781:   proj role (round-15 proven 512-thr body; no dst copy).
// blocks 782..797: embed role (proven MFMA body).
// blocks 798..861: compose role (proven body).
// All three roles are mutually independent and independent of prior launches.
__global__ __launch_bounds__(512, 2) void k_stage1(
    const float* __restrict__ mem, const float* __restrict__ b_tsq,
    const float* __restrict__ W_tsq,
    const float* __restrict__ s, const float* __restrict__ t,
    const float* __restrict__ W_es, const float* __restrict__ b_es,
    const float* __restrict__ W_et, const float* __restrict__ b_et,
    const float* __restrict__ W_mts, const float* __restrict__ b_mts,
    const float* __restrict__ W_hts, const float* __restrict__ b_hts,
    const float* __restrict__ W_mt,  const float* __restrict__ b_mt,
    const float* __restrict__ W_ht,  const float* __restrict__ b_ht,
    float* __restrict__ ws, float* __restrict__ proj)
{
    __shared__ __align__(16) char smem[65536];
    short* Bh = (short*)smem;
    short* Bl = (short*)(smem + 32768);
    int bid = blockIdx.x, tid = threadIdx.x;

    if (bid < 782) {
        // ---- proj role: self-split W_tsq into LDS B-fragments ----
        {
            int d = tid >> 2, k0 = (tid & 3) * 32;
            int tt = d >> 4, col = d & 15;
            #pragma unroll
            for (int h = 0; h < 4; ++h) {
                int k = k0 + h * 8;
                float4 x0 = *(const float4*)&W_tsq[d * 128 + k];
                float4 x1 = *(const float4*)&W_tsq[d * 128 + k + 4];
                short8v h8, l8; split8(x0, x1, h8, l8);
                int c = k >> 5, kg = (k >> 3) & 3;
                int a2 = (((tt * 4 + c) * 4 + kg) * 16 + col) * 8;
                *(short8v*)&Bh[a2] = h8;
                *(short8v*)&Bl[a2] = l8;
            }
        }
        __syncthreads();

        int lane = tid & 63, w = tid >> 6;
        int g = bid * 8 + w;
        if (g >= 6250) return;

        int col = lane & 15, rq = lane >> 4;
        long rowA = (long)g * 16 + col;
        int kg = rq * 8;
        const float* src = mem + rowA * 128;

        short8v ah[4], al[4];
        #pragma unroll
        for (int c = 0; c < 4; ++c) {
            int ko = c * 32 + kg;
            float4 x0 = *(const float4*)&src[ko];
            float4 x1 = *(const float4*)&src[ko + 4];
            split8(x0, x1, ah[c], al[c]);
        }

        #pragma unroll
        for (int t2 = 0; t2 < 8; ++t2) {
            float b0 = b_tsq[t2 * 16 + col];
            f32x4 a; a[0] = b0; a[1] = b0; a[2] = b0; a[3] = b0;
            #pragma unroll
            for (int c = 0; c < 4; ++c) {
                int off = ((t2 * 4 + c) * 64 + lane) * 8;
                short8v bh = *(const short8v*)&Bh[off];
                short8v bl = *(const short8v*)&Bl[off];
                a = __builtin_amdgcn_mfma_f32_16x16x32_bf16(al[c], bh, a, 0, 0, 0);
                a = __builtin_amdgcn_mfma_f32_16x16x32_bf16(ah[c], bl, a, 0, 0, 0);
                a = __builtin_amdgcn_mfma_f32_16x16x32_bf16(ah[c], bh, a, 0, 0, 0);
            }
            #pragma unroll
            for (int r = 0; r < 4; ++r)
                proj[((long)g * 16 + rq * 4 + r) * 128 + t2 * 16 + col] = a[r];
        }
        return;
    }

    if (bid < 798) {
        // ---- embed role ----
        float (*red)[2048] = (float(*)[2048])smem;
        int eb = bid - 782;            // 0..15
        int which = eb >> 3;           // 0: se, 1: te
        int grp = eb & 7;
        const float* x    = which ? t : s;
        const float* W    = which ? W_et : W_es;
        const float* bias = which ? b_et : b_es;

        int lane = tid & 63, w = tid >> 6;
        int col = lane & 15, rq = lane >> 4;
        const float* xr = x + (long)(grp * 16 + col) * 1024;

        f32x4 acc[8];
        #pragma unroll
        for (int t2 = 0; t2 < 8; ++t2) {
            acc[t2][0] = 0.f; acc[t2][1] = 0.f; acc[t2][2] = 0.f; acc[t2][3] = 0.f;
        }

        #pragma unroll
        for (int c = 0; c < 4; ++c) {
            int kb = w * 128 + c * 32 + rq * 8;
            short8v ah, al;
            {
                float4 x0 = *(const float4*)&xr[kb];
                float4 x1 = *(const float4*)&xr[kb + 4];
                split8(x0, x1, ah, al);
            }
            #pragma unroll
            for (int t2 = 0; t2 < 8; ++t2) {
                const float* wr = W + (long)(t2 * 16 + col) * 1024 + kb;
                float4 w0 = *(const float4*)&wr[0];
                float4 w1 = *(const float4*)&wr[4];
                short8v bh, bl; split8(w0, w1, bh, bl);
                acc[t2] = __builtin_amdgcn_mfma_f32_16x16x32_bf16(al, bh, acc[t2], 0, 0, 0);
                acc[t2] = __builtin_amdgcn_mfma_f32_16x16x32_bf16(ah, bl, acc[t2], 0, 0, 0);
                acc[t2] = __builtin_amdgcn_mfma_f32_16x16x32_bf16(ah, bh, acc[t2], 0, 0, 0);
            }
        }

        #pragma unroll
        for (int t2 = 0; t2 < 8; ++t2)
            #pragma unroll
            for (int r = 0; r < 4; ++r)
                red[w][(rq * 4 + r) * 128 + t2 * 16 + col] = acc[t2][r];
        __syncthreads();

        for (int i = tid; i < 2048; i += 512) {
            float sum = 0.f;
            #pragma unroll
            for (int w2 = 0; w2 < 8; ++w2) sum += red[w2][i];
            int rl = i >> 7, d = i & 127;
            ws[(which ? WS_TE : WS_SE) + (grp * 16 + rl) * 128 + d] = sum + bias[d];
        }
        return;
    }

    // ---- compose role ----
    {
        int cb = bid - 798;            // 0..63
        int which = cb >> 5;           // 0: ts, 1: t
        int sub = cb & 31;
        const float* A  = which ? W_ht : W_hts;
        const float* Bm = which ? W_mt : W_mts;
        short* FH = (short*)(ws + (which ? FR_T_HI : FR_TS_HI));
        short* FL = (short*)(ws + (which ? FR_T_LO : FR_TS_LO));

        int d = sub * 4 + (tid >> 7); // wave-uniform
        int k = tid & 127;
        const float* Ar = A + d * 128;
        float acc = 0.f;
        #pragma unroll 8
        for (int m = 0; m < 128; ++m)
            acc = fmaf(Ar[m], Bm[m * 128 + k], acc);

        int t2 = d >> 4, col = d & 15, c = k >> 5, kg = (k >> 3) & 3, e = k & 7;
        int a2 = (((t2 * 4 + c) * 4 + kg) * 16 + col) * 8 + e;
        unsigned short h, l; splits(acc, h, l);
        FH[a2] = (short)h;
        FL[a2] = (short)l;

        if (sub == 0 && tid < 128) {
            const float* bin  = which ? b_mt : b_mts;
            const float* bout = which ? b_ht : b_hts;
            float a = bout[tid];
            #pragma unroll 8
            for (int m = 0; m < 128; ++m) a = fmaf(A[tid * 128 + m], bin[m], a);
            ws[(which ? BC_T : BC_TS) + tid] = a;
        }
    }
}

// ---------------------------------------------------------------- k_proj4
// standalone: 128 blocks x 512, 4 rows per block (proven body).
__global__ __launch_bounds__(512, 2) void k_proj4(
    const float* __restrict__ W_tv,  const float* __restrict__ b_tv,
    const float* __restrict__ W_tq,  const float* __restrict__ b_tq,
    const float* __restrict__ W_tsv, const float* __restrict__ b_tsv,
    const float* __restrict__ W_tsq, const float* __restrict__ b_tsq,
    float* __restrict__ ws)
{
    int pb = blockIdx.x;
    int tid = threadIdx.x;
    int gi = tid >> 7, d = tid & 127;
    int rr = pb * 4 + gi;
    int which = rr >> 7, r = rr & 127;
    const float *W, *bias, *in;
    float* outp;
    switch (which) {
        case 0:  W = W_tv;  bias = b_tv;  in = ws + WS_TE; outp = ws + WS_MTV;  break;
        case 1:  W = W_tq;  bias = b_tq;  in = ws + WS_TE; outp = ws + WS_MTQ;  break;
        case 2:  W = W_tsv; bias = b_tsv; in = ws + WS_TE; outp = ws + WS_MSV;  break;
        default: W = W_tsq; bias = b_tsq; in = ws + WS_SE; outp = ws + WS_MSPQ; break;
    }
    const float* xr = in + r * DD;
    const float* Wr = W + d * DD;
    float a0 = 0.f, a1 = 0.f, a2 = 0.f, a3 = 0.f;
    #pragma unroll
    for (int k = 0; k < DD; k += 16) {
        float4 xv0 = *(const float4*)&xr[k],      wv0 = *(const float4*)&Wr[k];
        float4 xv1 = *(const float4*)&xr[k + 4],  wv1 = *(const float4*)&Wr[k + 4];
        float4 xv2 = *(const float4*)&xr[k + 8],  wv2 = *(const float4*)&Wr[k + 8];
        float4 xv3 = *(const float4*)&xr[k + 12], wv3 = *(const float4*)&Wr[k + 12];
        a0 = fmaf(xv0.x, wv0.x, fmaf(xv0.y, wv0.y, fmaf(xv0.z, wv0.z, fmaf(xv0.w, wv0.w, a0))));
        a1 = fmaf(xv1.x, wv1.x, fmaf(xv1.y, wv1.y, fmaf(xv1.z, wv1.z, fmaf(xv1.w, wv1.w, a1))));
        a2 = fmaf(xv2.x, wv2.x, fmaf(xv2.y, wv2.y, fmaf(xv2.z, wv2.z, fmaf(xv2.w, wv2.w, a2))));
        a3 = fmaf(xv3.x, wv3.x, fmaf(xv3.y, wv3.y, fmaf(xv3.z, wv3.z, fmaf(xv3.w, wv3.w, a3))));
    }
    outp[r * DD + d] = bias[d] + ((a0 + a1) + (a2 + a3));
}

// ---------------------------------------------------------------- k_ht
// standalone, proven round-12 geometry: 128 blocks x 512, 8 groups/block.
__global__ __launch_bounds__(512, 2) void k_ht(float* __restrict__ ws)
{
    __shared__ short Bh[16384], Bl[16384];
    const short* frh = (const short*)(ws + FR_T_HI);
    const short* frl = (const short*)(ws + FR_T_LO);
    int tid = threadIdx.x;
    for (int i2 = tid; i2 < 2048; i2 += 512) {
        ((uint4*)Bh)[i2] = ((const uint4*)frh)[i2];
        ((uint4*)Bl)[i2] = ((const uint4*)frl)[i2];
    }
    __syncthreads();

    const float* mtv = ws + WS_MTV;
    const float* mtq = ws + WS_MTQ;
    const float* bc  = ws + BC_T;
    float* ht = ws + WS_HT;

    int lane = tid & 63, w = tid >> 6;
    int col = lane & 15, rq = lane >> 4;
    int g = blockIdx.x * 8 + w;
    int p = g * 16 + col;
    int i = p >> 7, j = p & 127;
    int kg = rq * 8;
    const float* vj = mtv + j * 128;
    const float* qi = mtq + i * 128;

    short8v ah[4], al[4];
    #pragma unroll
    for (int c = 0; c < 4; ++c) {
        int ko = c * 32 + kg;
        float4 v0 = *(const float4*)&vj[ko], v1 = *(const float4*)&vj[ko + 4];
        float4 q0 = *(const float4*)&qi[ko], q1 = *(const float4*)&qi[ko + 4];
        float4 r0 = make_float4(fmaxf(v0.x - q0.x, 0.f), fmaxf(v0.y - q0.y, 0.f),
                                fmaxf(v0.z - q0.z, 0.f), fmaxf(v0.w - q0.w, 0.f));
        float4 r1 = make_float4(fmaxf(v1.x - q1.x, 0.f), fmaxf(v1.y - q1.y, 0.f),
                                fmaxf(v1.z - q1.z, 0.f), fmaxf(v1.w - q1.w, 0.f));
        split8(r0, r1, ah[c], al[c]);
    }

    f32x4 acc[8];
    #pragma unroll
    for (int t = 0; t < 8; ++t) {
        float b0 = bc[t * 16 + col];
        f32x4 a; a[0] = b0; a[1] = b0; a[2] = b0; a[3] = b0;
        #pragma unroll
        for (int c = 0; c < 4; ++c) {
            int off = ((t * 4 + c) * 64 + lane) * 8;
            short8v bh = *(const short8v*)&Bh[off];
            short8v bl = *(const short8v*)&Bl[off];
            a = __builtin_amdgcn_mfma_f32_16x16x32_bf16(al[c], bh, a, 0, 0, 0);
            a = __builtin_amdgcn_mfma_f32_16x16x32_bf16(ah[c], bl, a, 0, 0, 0);
            a = __builtin_amdgcn_mfma_f32_16x16x32_bf16(ah[c], bh, a, 0, 0, 0);
        }
        acc[t] = a;
    }

    #pragma unroll
    for (int r = 0; r < 4; ++r) {
        long rho = g * 16 + rq * 4 + r;
        float s_uu = 0.f;
        #pragma unroll
        for (int t = 0; t < 8; ++t) { float u = acc[t][r]; s_uu = fmaf(u, u, s_uu); }
        #pragma unroll
        for (int m = 1; m < 16; m <<= 1) s_uu += __shfl_xor(s_uu, m);
        float rn = rsqrtf(s_uu);
        #pragma unroll
        for (int t = 0; t < 8; ++t)
            ht[rho * 128 + t * 16 + col] = acc[t][r] * rn;
    }
}

// ---------------------------------------------------------------- k_neg_mfma
// blocks 0..1087: proven compute body (1024 thr, 32 waves/CU, XCD swizzle).
// blocks 1088..1215: memory_new copy role (102MB BW work in k_neg's headroom).
__global__ __launch_bounds__(1024, 8) void k_neg_mfma(
    const float* __restrict__ ws, const int* __restrict__ idx,
    const float* __restrict__ proj, float* __restrict__ out,
    const float* __restrict__ mem, float* __restrict__ dst)
{
    int tid = threadIdx.x;
    if (blockIdx.x >= 1088) {
        long n4 = (long)NMEM * 128 / 4;
        long i = (long)(blockIdx.x - 1088) * 1024 + tid;
        for (; i < n4; i += 128 * 1024)
            ((float4*)dst)[i] = ((const float4*)mem)[i];
        return;
    }

    __shared__ short Bh[16384], Bl[16384];
    const short* frh = (const short*)(ws + FR_TS_HI);
    const short* frl = (const short*)(ws + FR_TS_LO);
    for (int i2 = tid; i2 < 2048; i2 += 1024) {
        ((uint4*)Bh)[i2] = ((const uint4*)frh)[i2];
        ((uint4*)Bl)[i2] = ((const uint4*)frl)[i2];
    }
    __syncthreads();

    const float* msv  = ws + WS_MSV;
    const float* mspq = ws + WS_MSPQ;
    const float* ht   = ws + WS_HT;
    const float* bc   = ws + BC_TS;

    int lane = tid & 63, w = tid >> 6;
    int col = lane & 15, rq = lane >> 4;
    int bswz = (blockIdx.x & 7) * 136 + (blockIdx.x >> 3);
    int g = bswz * 16 + w;

    int rowA = g * 16 + col;
    int p = rowA / 17;
    int slot = rowA - p * 17;
    const float* src = slot ? (proj + (long)idx[p * 17 + slot - 1] * 128)
                            : (mspq + (p >> 7) * 128);
    const float* vj = msv + (p & 127) * 128;
    int kg = rq * 8;

    short8v ah[4], al[4];
    #pragma unroll
    for (int c = 0; c < 4; ++c) {
        int ko = c * 32 + kg;
        float4 v0 = *(const float4*)&vj[ko],  v1 = *(const float4*)&vj[ko + 4];
        float4 q0 = *(const float4*)&src[ko], q1 = *(const float4*)&src[ko + 4];
        float4 r0 = make_float4(fmaxf(v0.x - q0.x, 0.f), fmaxf(v0.y - q0.y, 0.f),
                                fmaxf(v0.z - q0.z, 0.f), fmaxf(v0.w - q0.w, 0.f));
        float4 r1 = make_float4(fmaxf(v1.x - q1.x, 0.f), fmaxf(v1.y - q1.y, 0.f),
                                fmaxf(v1.z - q1.z, 0.f), fmaxf(v1.w - q1.w, 0.f));
        split8(r0, r1, ah[c], al[c]);
    }

    f32x4 acc[8];
    #pragma unroll
    for (int t = 0; t < 8; ++t) {
        float b0 = bc[t * 16 + col];
        f32x4 a; a[0] = b0; a[1] = b0; a[2] = b0; a[3] = b0;
        #pragma unroll
        for (int c = 0; c < 4; ++c) {
            int off = ((t * 4 + c) * 64 + lane) * 8;
            short8v bh = *(const short8v*)&Bh[off];
            short8v bl = *(const short8v*)&Bl[off];
            a = __builtin_amdgcn_mfma_f32_16x16x32_bf16(al[c], bh, a, 0, 0, 0);
            a = __builtin_amdgcn_mfma_f32_16x16x32_bf16(ah[c], bl, a, 0, 0, 0);
            a = __builtin_amdgcn_mfma_f32_16x16x32_bf16(ah[c], bh, a, 0, 0, 0);
        }
        acc[t] = a;
    }

    #pragma unroll
    for (int r = 0; r < 4; ++r) {
        int rho = g * 16 + rq * 4 + r;
        int pe = rho / 17;
        const float* hrow = ht + (long)pe * 128 + col;
        float s_uu = 0.f, s_hu = 0.f;
        #pragma unroll
        for (int t = 0; t < 8; ++t) {
            float u = acc[t][r];
            s_uu = fmaf(u, u, s_uu);
            s_hu = fmaf(hrow[t * 16], u, s_hu);
        }
        #pragma unroll
        for (int m = 1; m < 16; m <<= 1) {
            s_uu += __shfl_xor(s_uu, m);
            s_hu += __shfl_xor(s_hu, m);
        }
        if (col == 0)
            out[rho] = __expf((s_hu * rsqrtf(s_uu) - 1.0f) * INV_T);
    }
}

// ---------------------------------------------------------------- k_memupd
__global__ __launch_bounds__(128) void k_memupd(
    const float* __restrict__ mem, const float* __restrict__ se,
    const int* __restrict__ y, float* __restrict__ dst)
{
    int b = blockIdx.x;
    int d = threadIdx.x;
    int yb = y[b];
    for (int b2 = b + 1; b2 < BB; ++b2)
        if (y[b2] == yb) return;

    float ab = 0.5f * mem[(long)yb * 128 + d] + 0.5f * se[b * 128 + d];
    float ss = ab * ab;
    #pragma unroll
    for (int mq = 32; mq; mq >>= 1) ss += __shfl_xor(ss, mq);
    __shared__ float partial[2];
    if ((d & 63) == 0) partial[d >> 6] = ss;
    __syncthreads();
    float tot = partial[0] + partial[1];
    dst[(long)yb * 128 + d] = ab * rsqrtf(tot);
}

// ---------------------------------------------------------------- launch
extern "C" void kernel_launch(void* const* d_in, const int* in_sizes, int n_in,
                              void* d_out, int out_size, void* d_ws, size_t ws_size,
                              hipStream_t stream)
{
    const float* s     = (const float*)d_in[0];
    const float* t     = (const float*)d_in[1];
    const int*   y     = (const int*)  d_in[2];
    const int*   idx   = (const int*)  d_in[3];
    const float* mem   = (const float*)d_in[4];
    const float* W_es  = (const float*)d_in[5];  const float* b_es  = (const float*)d_in[6];
    const float* W_et  = (const float*)d_in[7];  const float* b_et  = (const float*)d_in[8];
    const float* W_tv  = (const float*)d_in[9];  const float* b_tv  = (const float*)d_in[10];
    const float* W_tq  = (const float*)d_in[11]; const float* b_tq  = (const float*)d_in[12];
    const float* W_tsv = (const float*)d_in[13]; const float* b_tsv = (const float*)d_in[14];
    const float* W_tsq = (const float*)d_in[15]; const float* b_tsq = (const float*)d_in[16];
    const float* W_mt  = (const float*)d_in[17]; const float* b_mt  = (const float*)d_in[18];
    const float* W_mts = (const float*)d_in[19]; const float* b_mts = (const float*)d_in[20];
    const float* W_ht  = (const float*)d_in[21]; const float* b_ht  = (const float*)d_in[22];
    const float* W_hts = (const float*)d_in[23]; const float* b_hts = (const float*)d_in[24];

    float* out  = (float*)d_out;
    float* ws   = (float*)d_ws;
    float* proj = ws + WS_PROJ;

    k_stage1  <<<862, 512, 0, stream>>>(mem, b_tsq, W_tsq,
                                        s, t, W_es, b_es, W_et, b_et,
                                        W_mts, b_mts, W_hts, b_hts,
                                        W_mt, b_mt, W_ht, b_ht, ws, proj);
    k_proj4   <<<128, 512, 0, stream>>>(W_tv, b_tv, W_tq, b_tq, W_tsv, b_tsv,
                                        W_tsq, b_tsq, ws);
    k_ht      <<<128, 512, 0, stream>>>(ws);
    k_neg_mfma<<<1216, 1024, 0, stream>>>(ws, idx, proj, out, mem, out + OUT_MEM);
    k_memupd  <<<128, 128, 0, stream>>>(mem, ws + WS_SE, y, out + OUT_MEM);
}

// Round 20
// 117.562 us; speedup vs baseline: 1.0141x; 1.0141x over previous
//
#include <hip/hip_runtime.h>

// RelationMemory — Round 20: FINAL. Byte-for-byte the round-16/18 proven best
// (117.6-117.7us, reproduced twice). Plateau confirmed across 6 arrangements
// (R12/14/15/16/18/19: 117.6-119.2). Ledger: setprio(-), XCD swizzle(0),
// R=2/seq2/inloop-ht(-), pre2c-1024(+1, kept), copy-in-kneg(0, kept),
// proj4-fold(-48), regroup(-1.6). Constraints: ~330MB HBM traffic (~52us),
// k_neg latency chains at max occupancy, 4-deep serial chain. Pure-bf16
// (dropping hi/lo split) fails the 7.66e-3 absmax budget (14.3x amplification).
//
// Chain: pre1b(embed+compose) -> proj4 -> pre2c(proj || ht) -> k_neg(+copy) -> memupd
//
// Algebra: linear(linear(x,Wm,bm),Wh,bh) == linear(x, Wh@Wm, Wh@bm+bh).
// MFMA: v_mfma_f32_16x16x32_bf16, fp32 via bf16 hi/lo split, 3 products
// (ah*bh + ah*bl + al*bh), rel err ~2^-17.
// Fragments: A row=lane&15, k=(lane>>4)*8+e; B col=lane&15; D row=(lane>>4)*4+r.

#define BB   128
#define DD   128
#define KK   16
#define NMEM 100000

static constexpr float INV_T = 1.0f / 0.07f;

// ws layout (float offsets)
#define WS_SE    0
#define WS_TE    16384
#define WS_MTV   32768
#define WS_MTQ   49152
#define WS_MSV   65536
#define WS_MSPQ  81920
#define WS_HT    98304            // 16384*128 floats -> ends 2195456
#define FR_TS_HI 2195456          // frag arrays: 16384 shorts = 8192 floats each
#define FR_TS_LO 2203648
#define FR_T_HI  2211840
#define FR_T_LO  2220032
#define BC_TS    2244608          // 128 floats
#define BC_T     2244736
#define WS_PROJ  2244864          // 100000*128 floats (51.2 MB)
#define OUT_MEM  278528           // memory_new offset in d_out

typedef __attribute__((ext_vector_type(8))) short short8v;
typedef __attribute__((ext_vector_type(4))) float f32x4;

// ---- cheap split: hi = bf16 half-up(x), lo = bf16 half-up(x - hi) ----
__device__ inline void split2(float x0, float x1, unsigned& hi, unsigned& lo) {
    unsigned u0 = __float_as_uint(x0), u1 = __float_as_uint(x1);
    unsigned h0 = (u0 + 0x8000u) & 0xffff0000u;
    unsigned h1 = (u1 + 0x8000u) & 0xffff0000u;
    float l0 = x0 - __uint_as_float(h0);
    float l1 = x1 - __uint_as_float(h1);
    unsigned v0 = __float_as_uint(l0) + 0x8000u;
    unsigned v1 = __float_as_uint(l1) + 0x8000u;
    hi = __builtin_amdgcn_perm(h1, h0, 0x07060302u);
    lo = __builtin_amdgcn_perm(v1, v0, 0x07060302u);
}

__device__ inline void split8(const float4& x0, const float4& x1, short8v& h8, short8v& l8) {
    uint4 H, L;
    split2(x0.x, x0.y, H.x, L.x);
    split2(x0.z, x0.w, H.y, L.y);
    split2(x1.x, x1.y, H.z, L.z);
    split2(x1.z, x1.w, H.w, L.w);
    h8 = *(short8v*)&H;
    l8 = *(short8v*)&L;
}

// scalar split (matches split2 bit-exactly)
__device__ inline void splits(float x, unsigned short& h, unsigned short& l) {
    unsigned u = __float_as_uint(x);
    unsigned hu = (u + 0x8000u) & 0xffff0000u;
    float lf = x - __uint_as_float(hu);
    h = (unsigned short)(hu >> 16);
    l = (unsigned short)((__float_as_uint(lf) + 0x8000u) >> 16);
}

// ---------------------------------------------------------------- k_pre1b
// blocks 0..15:  embed role (MFMA).
// blocks 16..79: compose role (4 d per block, one element Wc[d,k]/thread).
__global__ __launch_bounds__(512, 2) void k_pre1b(
    const float* __restrict__ s, const float* __restrict__ t,
    const float* __restrict__ W_es, const float* __restrict__ b_es,
    const float* __restrict__ W_et, const float* __restrict__ b_et,
    const float* __restrict__ W_mts, const float* __restrict__ b_mts,
    const float* __restrict__ W_hts, const float* __restrict__ b_hts,
    const float* __restrict__ W_mt,  const float* __restrict__ b_mt,
    const float* __restrict__ W_ht,  const float* __restrict__ b_ht,
    float* __restrict__ ws)
{
    __shared__ float red[8][2048];
    int bid = blockIdx.x, tid = threadIdx.x;

    if (bid >= 16) {
        // ---- compose role ----
        int cb = bid - 16;             // 0..63
        int which = cb >> 5;           // 0: ts, 1: t
        int sub = cb & 31;
        const float* A  = which ? W_ht : W_hts;
        const float* Bm = which ? W_mt : W_mts;
        short* FH = (short*)(ws + (which ? FR_T_HI : FR_TS_HI));
        short* FL = (short*)(ws + (which ? FR_T_LO : FR_TS_LO));

        int d = sub * 4 + (tid >> 7); // wave-uniform
        int k = tid & 127;
        const float* Ar = A + d * 128;
        float acc = 0.f;
        #pragma unroll 8
        for (int m = 0; m < 128; ++m)
            acc = fmaf(Ar[m], Bm[m * 128 + k], acc);

        int t2 = d >> 4, col = d & 15, c = k >> 5, kg = (k >> 3) & 3, e = k & 7;
        int a2 = (((t2 * 4 + c) * 4 + kg) * 16 + col) * 8 + e;
        unsigned short h, l; splits(acc, h, l);
        FH[a2] = (short)h;
        FL[a2] = (short)l;

        if (sub == 0 && tid < 128) {
            const float* bin  = which ? b_mt : b_mts;
            const float* bout = which ? b_ht : b_hts;
            float a = bout[tid];
            #pragma unroll 8
            for (int m = 0; m < 128; ++m) a = fmaf(A[tid * 128 + m], bin[m], a);
            ws[(which ? BC_T : BC_TS) + tid] = a;
        }
        return;
    }

    // ---- embed role ----
    int which = bid >> 3;          // 0: se, 1: te
    int grp = bid & 7;
    const float* x    = which ? t : s;
    const float* W    = which ? W_et : W_es;
    const float* bias = which ? b_et : b_es;

    int lane = tid & 63, w = tid >> 6;
    int col = lane & 15, rq = lane >> 4;
    const float* xr = x + (long)(grp * 16 + col) * 1024;

    f32x4 acc[8];
    #pragma unroll
    for (int t2 = 0; t2 < 8; ++t2) {
        acc[t2][0] = 0.f; acc[t2][1] = 0.f; acc[t2][2] = 0.f; acc[t2][3] = 0.f;
    }

    #pragma unroll
    for (int c = 0; c < 4; ++c) {
        int kb = w * 128 + c * 32 + rq * 8;
        short8v ah, al;
        {
            float4 x0 = *(const float4*)&xr[kb];
            float4 x1 = *(const float4*)&xr[kb + 4];
            split8(x0, x1, ah, al);
        }
        #pragma unroll
        for (int t2 = 0; t2 < 8; ++t2) {
            const float* wr = W + (long)(t2 * 16 + col) * 1024 + kb;
            float4 w0 = *(const float4*)&wr[0];
            float4 w1 = *(const float4*)&wr[4];
            short8v bh, bl; split8(w0, w1, bh, bl);
            acc[t2] = __builtin_amdgcn_mfma_f32_16x16x32_bf16(al, bh, acc[t2], 0, 0, 0);
            acc[t2] = __builtin_amdgcn_mfma_f32_16x16x32_bf16(ah, bl, acc[t2], 0, 0, 0);
            acc[t2] = __builtin_amdgcn_mfma_f32_16x16x32_bf16(ah, bh, acc[t2], 0, 0, 0);
        }
    }

    #pragma unroll
    for (int t2 = 0; t2 < 8; ++t2)
        #pragma unroll
        for (int r = 0; r < 4; ++r)
            red[w][(rq * 4 + r) * 128 + t2 * 16 + col] = acc[t2][r];
    __syncthreads();

    for (int i = tid; i < 2048; i += 512) {
        float sum = 0.f;
        #pragma unroll
        for (int w2 = 0; w2 < 8; ++w2) sum += red[w2][i];
        int rl = i >> 7, d = i & 127;
        ws[(which ? WS_TE : WS_SE) + (grp * 16 + rl) * 128 + d] = sum + bias[d];
    }
}

// ---------------------------------------------------------------- k_proj4
// standalone: 128 blocks x 512, 4 rows per block (proven body).
__global__ __launch_bounds__(512, 2) void k_proj4(
    const float* __restrict__ W_tv,  const float* __restrict__ b_tv,
    const float* __restrict__ W_tq,  const float* __restrict__ b_tq,
    const float* __restrict__ W_tsv, const float* __restrict__ b_tsv,
    const float* __restrict__ W_tsq, const float* __restrict__ b_tsq,
    float* __restrict__ ws)
{
    int pb = blockIdx.x;
    int tid = threadIdx.x;
    int gi = tid >> 7, d = tid & 127;
    int rr = pb * 4 + gi;
    int which = rr >> 7, r = rr & 127;
    const float *W, *bias, *in;
    float* outp;
    switch (which) {
        case 0:  W = W_tv;  bias = b_tv;  in = ws + WS_TE; outp = ws + WS_MTV;  break;
        case 1:  W = W_tq;  bias = b_tq;  in = ws + WS_TE; outp = ws + WS_MTQ;  break;
        case 2:  W = W_tsv; bias = b_tsv; in = ws + WS_TE; outp = ws + WS_MSV;  break;
        default: W = W_tsq; bias = b_tsq; in = ws + WS_SE; outp = ws + WS_MSPQ; break;
    }
    const float* xr = in + r * DD;
    const float* Wr = W + d * DD;
    float a0 = 0.f, a1 = 0.f, a2 = 0.f, a3 = 0.f;
    #pragma unroll
    for (int k = 0; k < DD; k += 16) {
        float4 xv0 = *(const float4*)&xr[k],      wv0 = *(const float4*)&Wr[k];
        float4 xv1 = *(const float4*)&xr[k + 4],  wv1 = *(const float4*)&Wr[k + 4];
        float4 xv2 = *(const float4*)&xr[k + 8],  wv2 = *(const float4*)&Wr[k + 8];
        float4 xv3 = *(const float4*)&xr[k + 12], wv3 = *(const float4*)&Wr[k + 12];
        a0 = fmaf(xv0.x, wv0.x, fmaf(xv0.y, wv0.y, fmaf(xv0.z, wv0.z, fmaf(xv0.w, wv0.w, a0))));
        a1 = fmaf(xv1.x, wv1.x, fmaf(xv1.y, wv1.y, fmaf(xv1.z, wv1.z, fmaf(xv1.w, wv1.w, a1))));
        a2 = fmaf(xv2.x, wv2.x, fmaf(xv2.y, wv2.y, fmaf(xv2.z, wv2.z, fmaf(xv2.w, wv2.w, a2))));
        a3 = fmaf(xv3.x, wv3.x, fmaf(xv3.y, wv3.y, fmaf(xv3.z, wv3.z, fmaf(xv3.w, wv3.w, a3))));
    }
    outp[r * DD + d] = bias[d] + ((a0 + a1) + (a2 + a3));
}

// ---------------------------------------------------------------- k_pre2c
// 1024 thr / 16 waves, launch_bounds(1024,8) -> 32 waves/CU.
// blocks 0..390:   proj role (no dst copy — copy lives in k_neg), 16 groups/blk.
// blocks 391..454: ht role, 16 groups/blk.
__global__ __launch_bounds__(1024, 8) void k_pre2c(
    const float* __restrict__ mem, const float* __restrict__ b_tsq,
    const float* __restrict__ W_tsq,
    float* __restrict__ ws, float* __restrict__ proj)
{
    __shared__ short Bh[16384], Bl[16384];
    int bid = blockIdx.x, tid = threadIdx.x;

    if (bid < 391) {
        // ---- self-split W_tsq into LDS B-fragments (16 elems/thread) ----
        {
            int d = tid >> 3, k0 = (tid & 7) * 16;
            int tt = d >> 4, col = d & 15;
            #pragma unroll
            for (int h = 0; h < 2; ++h) {
                int k = k0 + h * 8;
                float4 x0 = *(const float4*)&W_tsq[d * 128 + k];
                float4 x1 = *(const float4*)&W_tsq[d * 128 + k + 4];
                short8v h8, l8; split8(x0, x1, h8, l8);
                int c = k >> 5, kg = (k >> 3) & 3;
                int a2 = (((tt * 4 + c) * 4 + kg) * 16 + col) * 8;
                *(short8v*)&Bh[a2] = h8;
                *(short8v*)&Bl[a2] = l8;
            }
        }
        __syncthreads();

        int lane = tid & 63, w = tid >> 6;
        int g = bid * 16 + w;
        if (g >= 6250) return;

        int col = lane & 15, rq = lane >> 4;
        long rowA = (long)g * 16 + col;
        int kg = rq * 8;
        const float* src = mem + rowA * 128;

        short8v ah[4], al[4];
        #pragma unroll
        for (int c = 0; c < 4; ++c) {
            int ko = c * 32 + kg;
            float4 x0 = *(const float4*)&src[ko];
            float4 x1 = *(const float4*)&src[ko + 4];
            split8(x0, x1, ah[c], al[c]);
        }

        #pragma unroll
        for (int t = 0; t < 8; ++t) {
            float b0 = b_tsq[t * 16 + col];
            f32x4 a; a[0] = b0; a[1] = b0; a[2] = b0; a[3] = b0;
            #pragma unroll
            for (int c = 0; c < 4; ++c) {
                int off = ((t * 4 + c) * 64 + lane) * 8;
                short8v bh = *(const short8v*)&Bh[off];
                short8v bl = *(const short8v*)&Bl[off];
                a = __builtin_amdgcn_mfma_f32_16x16x32_bf16(al[c], bh, a, 0, 0, 0);
                a = __builtin_amdgcn_mfma_f32_16x16x32_bf16(ah[c], bl, a, 0, 0, 0);
                a = __builtin_amdgcn_mfma_f32_16x16x32_bf16(ah[c], bh, a, 0, 0, 0);
            }
            #pragma unroll
            for (int r = 0; r < 4; ++r)
                proj[((long)g * 16 + rq * 4 + r) * 128 + t * 16 + col] = a[r];
        }
        return;
    }

    // ---- ht role ----
    {
        const short* frh = (const short*)(ws + FR_T_HI);
        const short* frl = (const short*)(ws + FR_T_LO);
        for (int i2 = tid; i2 < 2048; i2 += 1024) {
            ((uint4*)Bh)[i2] = ((const uint4*)frh)[i2];
            ((uint4*)Bl)[i2] = ((const uint4*)frl)[i2];
        }
        __syncthreads();

        const float* mtv = ws + WS_MTV;
        const float* mtq = ws + WS_MTQ;
        const float* bc  = ws + BC_T;
        float* ht = ws + WS_HT;

        int lane = tid & 63, w = tid >> 6;
        int col = lane & 15, rq = lane >> 4;
        int g = (bid - 391) * 16 + w;
        int p = g * 16 + col;
        int i = p >> 7, j = p & 127;
        int kg = rq * 8;
        const float* vj = mtv + j * 128;
        const float* qi = mtq + i * 128;

        short8v ah[4], al[4];
        #pragma unroll
        for (int c = 0; c < 4; ++c) {
            int ko = c * 32 + kg;
            float4 v0 = *(const float4*)&vj[ko], v1 = *(const float4*)&vj[ko + 4];
            float4 q0 = *(const float4*)&qi[ko], q1 = *(const float4*)&qi[ko + 4];
            float4 r0 = make_float4(fmaxf(v0.x - q0.x, 0.f), fmaxf(v0.y - q0.y, 0.f),
                                    fmaxf(v0.z - q0.z, 0.f), fmaxf(v0.w - q0.w, 0.f));
            float4 r1 = make_float4(fmaxf(v1.x - q1.x, 0.f), fmaxf(v1.y - q1.y, 0.f),
                                    fmaxf(v1.z - q1.z, 0.f), fmaxf(v1.w - q1.w, 0.f));
            split8(r0, r1, ah[c], al[c]);
        }

        f32x4 acc[8];
        #pragma unroll
        for (int t = 0; t < 8; ++t) {
            float b0 = bc[t * 16 + col];
            f32x4 a; a[0] = b0; a[1] = b0; a[2] = b0; a[3] = b0;
            #pragma unroll
            for (int c = 0; c < 4; ++c) {
                int off = ((t * 4 + c) * 64 + lane) * 8;
                short8v bh = *(const short8v*)&Bh[off];
                short8v bl = *(const short8v*)&Bl[off];
                a = __builtin_amdgcn_mfma_f32_16x16x32_bf16(al[c], bh, a, 0, 0, 0);
                a = __builtin_amdgcn_mfma_f32_16x16x32_bf16(ah[c], bl, a, 0, 0, 0);
                a = __builtin_amdgcn_mfma_f32_16x16x32_bf16(ah[c], bh, a, 0, 0, 0);
            }
            acc[t] = a;
        }

        #pragma unroll
        for (int r = 0; r < 4; ++r) {
            long rho = g * 16 + rq * 4 + r;
            float s_uu = 0.f;
            #pragma unroll
            for (int t = 0; t < 8; ++t) { float u = acc[t][r]; s_uu = fmaf(u, u, s_uu); }
            #pragma unroll
            for (int m = 1; m < 16; m <<= 1) s_uu += __shfl_xor(s_uu, m);
            float rn = rsqrtf(s_uu);
            #pragma unroll
            for (int t = 0; t < 8; ++t)
                ht[rho * 128 + t * 16 + col] = acc[t][r] * rn;
        }
    }
}

// ---------------------------------------------------------------- k_neg_mfma
// blocks 0..1087: proven compute body (1024 thr, 32 waves/CU, XCD swizzle).
// blocks 1088..1215: memory_new copy role (102MB BW work in k_neg's headroom).
__global__ __launch_bounds__(1024, 8) void k_neg_mfma(
    const float* __restrict__ ws, const int* __restrict__ idx,
    const float* __restrict__ proj, float* __restrict__ out,
    const float* __restrict__ mem, float* __restrict__ dst)
{
    int tid = threadIdx.x;
    if (blockIdx.x >= 1088) {
        long n4 = (long)NMEM * 128 / 4;
        long i = (long)(blockIdx.x - 1088) * 1024 + tid;
        for (; i < n4; i += 128 * 1024)
            ((float4*)dst)[i] = ((const float4*)mem)[i];
        return;
    }

    __shared__ short Bh[16384], Bl[16384];
    const short* frh = (const short*)(ws + FR_TS_HI);
    const short* frl = (const short*)(ws + FR_TS_LO);
    for (int i2 = tid; i2 < 2048; i2 += 1024) {
        ((uint4*)Bh)[i2] = ((const uint4*)frh)[i2];
        ((uint4*)Bl)[i2] = ((const uint4*)frl)[i2];
    }
    __syncthreads();

    const float* msv  = ws + WS_MSV;
    const float* mspq = ws + WS_MSPQ;
    const float* ht   = ws + WS_HT;
    const float* bc   = ws + BC_TS;

    int lane = tid & 63, w = tid >> 6;
    int col = lane & 15, rq = lane >> 4;
    int bswz = (blockIdx.x & 7) * 136 + (blockIdx.x >> 3);
    int g = bswz * 16 + w;

    int rowA = g * 16 + col;
    int p = rowA / 17;
    int slot = rowA - p * 17;
    const float* src = slot ? (proj + (long)idx[p * 17 + slot - 1] * 128)
                            : (mspq + (p >> 7) * 128);
    const float* vj = msv + (p & 127) * 128;
    int kg = rq * 8;

    short8v ah[4], al[4];
    #pragma unroll
    for (int c = 0; c < 4; ++c) {
        int ko = c * 32 + kg;
        float4 v0 = *(const float4*)&vj[ko],  v1 = *(const float4*)&vj[ko + 4];
        float4 q0 = *(const float4*)&src[ko], q1 = *(const float4*)&src[ko + 4];
        float4 r0 = make_float4(fmaxf(v0.x - q0.x, 0.f), fmaxf(v0.y - q0.y, 0.f),
                                fmaxf(v0.z - q0.z, 0.f), fmaxf(v0.w - q0.w, 0.f));
        float4 r1 = make_float4(fmaxf(v1.x - q1.x, 0.f), fmaxf(v1.y - q1.y, 0.f),
                                fmaxf(v1.z - q1.z, 0.f), fmaxf(v1.w - q1.w, 0.f));
        split8(r0, r1, ah[c], al[c]);
    }

    f32x4 acc[8];
    #pragma unroll
    for (int t = 0; t < 8; ++t) {
        float b0 = bc[t * 16 + col];
        f32x4 a; a[0] = b0; a[1] = b0; a[2] = b0; a[3] = b0;
        #pragma unroll
        for (int c = 0; c < 4; ++c) {
            int off = ((t * 4 + c) * 64 + lane) * 8;
            short8v bh = *(const short8v*)&Bh[off];
            short8v bl = *(const short8v*)&Bl[off];
            a = __builtin_amdgcn_mfma_f32_16x16x32_bf16(al[c], bh, a, 0, 0, 0);
            a = __builtin_amdgcn_mfma_f32_16x16x32_bf16(ah[c], bl, a, 0, 0, 0);
            a = __builtin_amdgcn_mfma_f32_16x16x32_bf16(ah[c], bh, a, 0, 0, 0);
        }
        acc[t] = a;
    }

    #pragma unroll
    for (int r = 0; r < 4; ++r) {
        int rho = g * 16 + rq * 4 + r;
        int pe = rho / 17;
        const float* hrow = ht + (long)pe * 128 + col;
        float s_uu = 0.f, s_hu = 0.f;
        #pragma unroll
        for (int t = 0; t < 8; ++t) {
            float u = acc[t][r];
            s_uu = fmaf(u, u, s_uu);
            s_hu = fmaf(hrow[t * 16], u, s_hu);
        }
        #pragma unroll
        for (int m = 1; m < 16; m <<= 1) {
            s_uu += __shfl_xor(s_uu, m);
            s_hu += __shfl_xor(s_hu, m);
        }
        if (col == 0)
            out[rho] = __expf((s_hu * rsqrtf(s_uu) - 1.0f) * INV_T);
    }
}

// ---------------------------------------------------------------- k_memupd
__global__ __launch_bounds__(128) void k_memupd(
    const float* __restrict__ mem, const float* __restrict__ se,
    const int* __restrict__ y, float* __restrict__ dst)
{
    int b = blockIdx.x;
    int d = threadIdx.x;
    int yb = y[b];
    for (int b2 = b + 1; b2 < BB; ++b2)
        if (y[b2] == yb) return;

    float ab = 0.5f * mem[(long)yb * 128 + d] + 0.5f * se[b * 128 + d];
    float ss = ab * ab;
    #pragma unroll
    for (int mq = 32; mq; mq >>= 1) ss += __shfl_xor(ss, mq);
    __shared__ float partial[2];
    if ((d & 63) == 0) partial[d >> 6] = ss;
    __syncthreads();
    float tot = partial[0] + partial[1];
    dst[(long)yb * 128 + d] = ab * rsqrtf(tot);
}

// ---------------------------------------------------------------- launch
extern "C" void kernel_launch(void* const* d_in, const int* in_sizes, int n_in,
                              void* d_out, int out_size, void* d_ws, size_t ws_size,
                              hipStream_t stream)
{
    const float* s     = (const float*)d_in[0];
    const float* t     = (const float*)d_in[1];
    const int*   y     = (const int*)  d_in[2];
    const int*   idx   = (const int*)  d_in[3];
    const float* mem   = (const float*)d_in[4];
    const float* W_es  = (const float*)d_in[5];  const float* b_es  = (const float*)d_in[6];
    const float* W_et  = (const float*)d_in[7];  const float* b_et  = (const float*)d_in[8];
    const float* W_tv  = (const float*)d_in[9];  const float* b_tv  = (const float*)d_in[10];
    const float* W_tq  = (const float*)d_in[11]; const float* b_tq  = (const float*)d_in[12];
    const float* W_tsv = (const float*)d_in[13]; const float* b_tsv = (const float*)d_in[14];
    const float* W_tsq = (const float*)d_in[15]; const float* b_tsq = (const float*)d_in[16];
    const float* W_mt  = (const float*)d_in[17]; const float* b_mt  = (const float*)d_in[18];
    const float* W_mts = (const float*)d_in[19]; const float* b_mts = (const float*)d_in[20];
    const float* W_ht  = (const float*)d_in[21]; const float* b_ht  = (const float*)d_in[22];
    const float* W_hts = (const float*)d_in[23]; const float* b_hts = (const float*)d_in[24];

    float* out  = (float*)d_out;
    float* ws   = (float*)d_ws;
    float* proj = ws + WS_PROJ;

    k_pre1b   <<<80, 512, 0, stream>>>(s, t, W_es, b_es, W_et, b_et,
                                       W_mts, b_mts, W_hts, b_hts,
                                       W_mt, b_mt, W_ht, b_ht, ws);
    k_proj4   <<<128, 512, 0, stream>>>(W_tv, b_tv, W_tq, b_tq, W_tsv, b_tsv,
                                        W_tsq, b_tsq, ws);
    k_pre2c   <<<455, 1024, 0, stream>>>(mem, b_tsq, W_tsq, ws, proj);
    k_neg_mfma<<<1216, 1024, 0, stream>>>(ws, idx, proj, out, mem, out + OUT_MEM);
    k_memupd  <<<128, 128, 0, stream>>>(mem, ws + WS_SE, y, out + OUT_MEM);
}